// Round 1
// 293.021 us; speedup vs baseline: 1.0296x; 1.0296x over previous
//
#include <hip/hip_runtime.h>
#include <math.h>

// Problem constants (from setup_inputs):
#define T_STEPS   4
#define NODE_NUM  10000
#define NUM_NODES 50000
#define E         256     // embedding dim
#define TWO_E     512
#define CC        128     // C
#define TWO_C     256
#define ROWS      32      // rows per block in the MLP kernel

typedef short bf16x8 __attribute__((ext_vector_type(8)));   // 8 bf16 = 4 VGPRs
typedef float f32x4  __attribute__((ext_vector_type(4)));   // MFMA accumulator

#define MFMA16(a, b, c) __builtin_amdgcn_mfma_f32_16x16x32_bf16((a), (b), (c), 0, 0, 0)

// bf16 weights, transposed [N][K], module-scope device global: d_ws is left
// entirely for the scatter table (the R2 ws-overrun fault is impossible here).
// layout (elements): w1t @0 (512x256), w2t @131072 (128x512),
//                    w1ut @196608 (256x128), w2ut @229376 (256x256)
static __device__ unsigned short g_wt[294912];
// per-(t, idx) occurrence count: rows with cnt==1 (~82%) skip the table
// entirely (identity scatter); only cnt>1 rows pay zero+atomicAdd.
static __device__ int g_cnt[T_STEPS * NUM_NODES];

__device__ __forceinline__ float geluf(float v) {
    return 0.5f * v * (1.0f + erff(v * 0.70710678118654752440f));
}

// fp32 -> bf16 round-to-nearest-even (finite inputs only)
__device__ __forceinline__ unsigned short f2bf(float f) {
    unsigned int u = __builtin_bit_cast(unsigned int, f);
    u += 0x7fffu + ((u >> 16) & 1u);
    return (unsigned short)(u >> 16);
}

// ---------------- weight prep: fp32 [K][N] -> bf16 [N][K]; also zero g_cnt ----
// grid 784 * 256 = 200704 threads covers all sections.
__global__ void prep_weights(const float* __restrict__ W1d, const float* __restrict__ W2d,
                             const float* __restrict__ W1u, const float* __restrict__ W2u) {
    int i = blockIdx.x * 256 + threadIdx.x;       // 0 .. 200703
    if (i < T_STEPS * NUM_NODES) g_cnt[i] = 0;    // 200000 counts
    if (i < 131072) {  // w1t: [512][256] <- W1d [256][512]
        int n = i >> 8, k = i & 255;
        g_wt[i] = f2bf(W1d[(size_t)k * TWO_E + n]);
    }
    if (i < 65536) {   // w2t: [128][512] <- W2d [512][128]
        int n = i >> 9, k = i & 511;
        g_wt[131072 + i] = f2bf(W2d[(size_t)k * CC + n]);
    }
    if (i < 32768) {   // w1ut: [256][128] <- W1u [128][256]
        int n = i >> 7, k = i & 127;
        g_wt[196608 + i] = f2bf(W1u[(size_t)k * TWO_C + n]);
    }
    if (i < 65536) {   // w2ut: [256][256] <- W2u [256][256]
        int n = i >> 8, k = i & 255;
        g_wt[229376 + i] = f2bf(W2u[(size_t)k * E + n]);
    }
}

// ---------------- count occurrences of each (t, idx) ----------------
__global__ void count_kernel(const int* __restrict__ indices) {
    int gr = blockIdx.x * 256 + threadIdx.x;
    if (gr < T_STEPS * NODE_NUM) {
        int t = gr / NODE_NUM;
        atomicAdd(&g_cnt[t * NUM_NODES + indices[gr]], 1);
    }
}

// ---------------- zero table rows for DUPLICATED indices only ----------------
__global__ void zero_dup_kernel(float* __restrict__ table,
                                const int* __restrict__ indices,
                                int gr0, int t0) {
    int gr = gr0 + blockIdx.x * 4 + (threadIdx.x >> 6);
    int t = gr / NODE_NUM;
    int idx = indices[gr];
    if (g_cnt[t * NUM_NODES + idx] < 2) return;   // wave-uniform branch
    int c = (threadIdx.x & 63) * 4;
    float4 z = make_float4(0.f, 0.f, 0.f, 0.f);
    *reinterpret_cast<float4*>(&table[((size_t)(t - t0) * NUM_NODES + idx) * E + c]) = z;
}

// ---------------- scatter-add for DUPLICATED indices only ----------------
__global__ void scatter_dup_kernel(float* __restrict__ table,
                                   const float* __restrict__ x,
                                   const int* __restrict__ indices,
                                   int gr0, int t0) {
    int gr = gr0 + blockIdx.x;
    int t = gr / NODE_NUM;
    int idx = indices[gr];
    if (g_cnt[t * NUM_NODES + idx] < 2) return;   // block-uniform branch
    atomicAdd(&table[((size_t)(t - t0) * NUM_NODES + idx) * E + threadIdx.x],
              x[(size_t)gr * E + threadIdx.x]);
}

// ---------------- fused gather -> LN_d -> MLP_d -> LN_u -> MLP_u ----------------
// 32 rows/block, 256 threads (4 waves). bf16 MFMA 16x16x32, fp32 accumulate.
// LDS aliasing (bytes):
//   region A [0, 33280):     Xf fp32 [32][260]  ->  H1 bf16 [32][520]
//                            -> H2b bf16 [32][136] @0 + G1 bf16 [32][264] @8704
//   region B [33280, 50176): Xs bf16 [32][264]  ->  H2f fp32 [32][132]
__global__ __launch_bounds__(256, 3)
void mlp_kernel(const float* __restrict__ table,
                const float* __restrict__ x,
                const float* __restrict__ batched_x,
                const int* __restrict__ indices,
                const float* __restrict__ lnd_s, const float* __restrict__ lnd_b,
                const float* __restrict__ b1d, const float* __restrict__ b2d,
                const float* __restrict__ lnu_s, const float* __restrict__ lnu_b,
                const float* __restrict__ b1u, const float* __restrict__ b2u,
                float* __restrict__ out,
                int gr0, int t0, int grLim) {
    __shared__ __align__(16) unsigned char smem[50176];
    __shared__ const float* rptr[ROWS];
    __shared__ int    ridx[ROWS];

    float*          Xf  = (float*)smem;                         // [32][260]
    unsigned short* Xs  = (unsigned short*)(smem + 33280);      // [32][264]
    unsigned short* H1  = (unsigned short*)smem;                // [32][520]
    float*          H2f = (float*)(smem + 33280);               // [32][132]
    unsigned short* H2b = (unsigned short*)smem;                // [32][136]
    unsigned short* G1  = (unsigned short*)(smem + 8704);       // [32][264]

    const unsigned short* w1t  = g_wt;
    const unsigned short* w2t  = g_wt + 131072;
    const unsigned short* w1ut = g_wt + 196608;
    const unsigned short* w2ut = g_wt + 229376;

    const int tid = threadIdx.x;
    const int w = tid >> 6, lane = tid & 63;
    const int l16 = lane & 15, quad = lane >> 4;
    const int grb = gr0 + blockIdx.x * ROWS;

    if (tid < ROWS) {
        int gr = grb + tid;
        if (gr >= grLim) gr = grLim - 1;     // clamped dup row; out-store guarded later
        int t = gr / NODE_NUM;
        int idx = indices[gr];
        ridx[tid] = idx;
        // unique index (82%): row input is just x[gr]; dup: read the summed table row
        rptr[tid] = (g_cnt[t * NUM_NODES + idx] > 1)
            ? (table + ((size_t)(t - t0) * NUM_NODES + idx) * E)
            : (x + (size_t)gr * E);
    }
    __syncthreads();

    // ---- gather: Xf = row_src + batched_x_row (fp32) ----
    #pragma unroll
    for (int it = 0; it < 8; ++it) {
        int v = it * 256 + tid;
        int r = v >> 6;
        int c = (v & 63) * 4;
        float4 tv = *reinterpret_cast<const float4*>(rptr[r] + c);
        float4 bv = *reinterpret_cast<const float4*>(&batched_x[(size_t)ridx[r] * E + c]);
        float4 s; s.x = tv.x + bv.x; s.y = tv.y + bv.y; s.z = tv.z + bv.z; s.w = tv.w + bv.w;
        *reinterpret_cast<float4*>(&Xf[r * 260 + c]) = s;
    }
    __syncthreads();

    // ---- LN_d (E=256): 8 lanes/row, then cvt bf16 -> Xs ----
    {
        int row = tid >> 3, l8 = tid & 7;
        float s = 0.f, sq = 0.f;
        #pragma unroll
        for (int k = 0; k < 32; ++k) {
            float v = Xf[row * 260 + k * 8 + l8];
            s += v; sq += v * v;
        }
        s  += __shfl_xor(s, 1);  s  += __shfl_xor(s, 2);  s  += __shfl_xor(s, 4);
        sq += __shfl_xor(sq, 1); sq += __shfl_xor(sq, 2); sq += __shfl_xor(sq, 4);
        float mu = s * (1.0f / E);
        float var = sq * (1.0f / E) - mu * mu;
        float rs = rsqrtf(var + 1e-5f);
        #pragma unroll
        for (int k = 0; k < 32; ++k) {
            int c = k * 8 + l8;
            float v = (Xf[row * 260 + c] - mu) * rs * lnd_s[c] + lnd_b[c];
            Xs[row * 264 + c] = f2bf(v);
        }
    }
    __syncthreads();

    // ---- GEMM1: H1[32][512] = gelu(Xs @ W1d + b1d), K=256 ----
    {
        bf16x8 af[2][8];
        #pragma unroll
        for (int mt = 0; mt < 2; ++mt) {
            const unsigned short* base = Xs + (l16 + 16 * mt) * 264 + quad * 8;
            #pragma unroll
            for (int ks = 0; ks < 8; ++ks)
                af[mt][ks] = *reinterpret_cast<const bf16x8*>(base + ks * 32);
        }
        #pragma unroll
        for (int nt_ = 0; nt_ < 8; ++nt_) {
            int n = (w * 8 + nt_) * 16 + l16;
            const unsigned short* bp = w1t + (size_t)n * 256 + quad * 8;
            f32x4 a0 = {0.f, 0.f, 0.f, 0.f}, a1 = {0.f, 0.f, 0.f, 0.f};
            #pragma unroll
            for (int ks = 0; ks < 8; ++ks) {
                bf16x8 b = *reinterpret_cast<const bf16x8*>(bp + ks * 32);
                a0 = MFMA16(af[0][ks], b, a0);
                a1 = MFMA16(af[1][ks], b, a1);
            }
            float bias = b1d[n];
            #pragma unroll
            for (int reg = 0; reg < 4; ++reg) {
                int r = quad * 4 + reg;
                H1[r * 520 + n]        = f2bf(geluf(a0[reg] + bias));
                H1[(r + 16) * 520 + n] = f2bf(geluf(a1[reg] + bias));
            }
        }
    }
    __syncthreads();

    // ---- GEMM2: H2f[32][128] = H1 @ W2d + b2d (fp32 out), K=512 ----
    {
        f32x4 acc2[2][2];
        #pragma unroll
        for (int i = 0; i < 2; ++i)
            #pragma unroll
            for (int j = 0; j < 2; ++j) acc2[i][j] = (f32x4){0.f, 0.f, 0.f, 0.f};
        #pragma unroll
        for (int kh = 0; kh < 2; ++kh) {
            bf16x8 af2[2][8];
            #pragma unroll
            for (int mt = 0; mt < 2; ++mt) {
                const unsigned short* base = H1 + (l16 + 16 * mt) * 520 + kh * 256 + quad * 8;
                #pragma unroll
                for (int ks = 0; ks < 8; ++ks)
                    af2[mt][ks] = *reinterpret_cast<const bf16x8*>(base + ks * 32);
            }
            #pragma unroll
            for (int nt2 = 0; nt2 < 2; ++nt2) {
                int n = (w * 2 + nt2) * 16 + l16;
                const unsigned short* bp = w2t + (size_t)n * 512 + kh * 256 + quad * 8;
                #pragma unroll
                for (int ks = 0; ks < 8; ++ks) {
                    bf16x8 b = *reinterpret_cast<const bf16x8*>(bp + ks * 32);
                    acc2[nt2][0] = MFMA16(af2[0][ks], b, acc2[nt2][0]);
                    acc2[nt2][1] = MFMA16(af2[1][ks], b, acc2[nt2][1]);
                }
            }
        }
        #pragma unroll
        for (int nt2 = 0; nt2 < 2; ++nt2) {
            int n = (w * 2 + nt2) * 16 + l16;
            float bias = b2d[n];
            #pragma unroll
            for (int mt = 0; mt < 2; ++mt)
                #pragma unroll
                for (int reg = 0; reg < 4; ++reg) {
                    int r = mt * 16 + quad * 4 + reg;
                    H2f[r * 132 + n] = acc2[nt2][mt][reg] + bias;
                }
        }
    }
    __syncthreads();

    // ---- LN_u (C=128): 8 lanes/row, cvt bf16 -> H2b ----
    {
        int row = tid >> 3, l8 = tid & 7;
        float s = 0.f, sq = 0.f;
        #pragma unroll
        for (int k = 0; k < 16; ++k) {
            float v = H2f[row * 132 + k * 8 + l8];
            s += v; sq += v * v;
        }
        s  += __shfl_xor(s, 1);  s  += __shfl_xor(s, 2);  s  += __shfl_xor(s, 4);
        sq += __shfl_xor(sq, 1); sq += __shfl_xor(sq, 2); sq += __shfl_xor(sq, 4);
        float mu = s * (1.0f / CC);
        float var = sq * (1.0f / CC) - mu * mu;
        float rs = rsqrtf(var + 1e-5f);
        #pragma unroll
        for (int k = 0; k < 16; ++k) {
            int c = k * 8 + l8;
            float v = (H2f[row * 132 + c] - mu) * rs * lnu_s[c] + lnu_b[c];
            H2b[row * 136 + c] = f2bf(v);
        }
    }
    __syncthreads();

    // ---- GEMM3: G1[32][256] = gelu(H2b @ W1u + b1u), K=128 ----
    {
        bf16x8 af3[2][4];
        #pragma unroll
        for (int mt = 0; mt < 2; ++mt) {
            const unsigned short* base = H2b + (l16 + 16 * mt) * 136 + quad * 8;
            #pragma unroll
            for (int ks = 0; ks < 4; ++ks)
                af3[mt][ks] = *reinterpret_cast<const bf16x8*>(base + ks * 32);
        }
        #pragma unroll
        for (int nt_ = 0; nt_ < 4; ++nt_) {
            int n = (w * 4 + nt_) * 16 + l16;
            const unsigned short* bp = w1ut + (size_t)n * 128 + quad * 8;
            f32x4 a0 = {0.f, 0.f, 0.f, 0.f}, a1 = {0.f, 0.f, 0.f, 0.f};
            #pragma unroll
            for (int ks = 0; ks < 4; ++ks) {
                bf16x8 b = *reinterpret_cast<const bf16x8*>(bp + ks * 32);
                a0 = MFMA16(af3[0][ks], b, a0);
                a1 = MFMA16(af3[1][ks], b, a1);
            }
            float bias = b1u[n];
            #pragma unroll
            for (int reg = 0; reg < 4; ++reg) {
                int r = quad * 4 + reg;
                G1[r * 264 + n]        = f2bf(geluf(a0[reg] + bias));
                G1[(r + 16) * 264 + n] = f2bf(geluf(a1[reg] + bias));
            }
        }
    }
    __syncthreads();

    // ---- GEMM4: out[32][256] = G1 @ W2u + b2u (fp32 global), K=256 ----
    {
        bf16x8 af4[2][8];
        #pragma unroll
        for (int mt = 0; mt < 2; ++mt) {
            const unsigned short* base = G1 + (l16 + 16 * mt) * 264 + quad * 8;
            #pragma unroll
            for (int ks = 0; ks < 8; ++ks)
                af4[mt][ks] = *reinterpret_cast<const bf16x8*>(base + ks * 32);
        }
        #pragma unroll
        for (int nt_ = 0; nt_ < 4; ++nt_) {
            int n = (w * 4 + nt_) * 16 + l16;
            const unsigned short* bp = w2ut + (size_t)n * 256 + quad * 8;
            f32x4 a0 = {0.f, 0.f, 0.f, 0.f}, a1 = {0.f, 0.f, 0.f, 0.f};
            #pragma unroll
            for (int ks = 0; ks < 8; ++ks) {
                bf16x8 b = *reinterpret_cast<const bf16x8*>(bp + ks * 32);
                a0 = MFMA16(af4[0][ks], b, a0);
                a1 = MFMA16(af4[1][ks], b, a1);
            }
            float bias = b2u[n];
            #pragma unroll
            for (int reg = 0; reg < 4; ++reg) {
                int r = quad * 4 + reg;
                int g0 = grb + r, g1 = grb + r + 16;
                if (g0 < grLim) out[(size_t)g0 * E + n] = a0[reg] + bias;
                if (g1 < grLim) out[(size_t)g1 * E + n] = a1[reg] + bias;
            }
        }
    }
}

extern "C" void kernel_launch(void* const* d_in, const int* in_sizes, int n_in,
                              void* d_out, int out_size, void* d_ws, size_t ws_size,
                              hipStream_t stream) {
    const float* x     = (const float*)d_in[0];
    const float* bx    = (const float*)d_in[1];
    const int*   idxp  = (const int*)  d_in[2];
    const float* lnd_s = (const float*)d_in[3];
    const float* lnd_b = (const float*)d_in[4];
    const float* W1d   = (const float*)d_in[5];
    const float* b1d   = (const float*)d_in[6];
    const float* W2d   = (const float*)d_in[7];
    const float* b2d   = (const float*)d_in[8];
    const float* lnu_s = (const float*)d_in[9];
    const float* lnu_b = (const float*)d_in[10];
    const float* W1u   = (const float*)d_in[11];
    const float* b1u   = (const float*)d_in[12];
    const float* W2u   = (const float*)d_in[13];
    const float* b2u   = (const float*)d_in[14];
    float* out = (float*)d_out;
    float* table = (float*)d_ws;     // full ws for table slices (weights in g_wt)

    const size_t slice_bytes = (size_t)NUM_NODES * E * sizeof(float);
    int tb = (int)(ws_size / slice_bytes);
    if (tb < 1) tb = 1;              // R1 passed with this assumption: ws >= 1 slice
    if (tb > T_STEPS) tb = T_STEPS;

    // weight transpose/cvt + g_cnt zeroing (fused), then the occurrence count
    prep_weights<<<784, 256, 0, stream>>>(W1d, W2d, W1u, W2u);
    count_kernel<<<(T_STEPS * NODE_NUM + 255) / 256, 256, 0, stream>>>(idxp);

    for (int t0 = 0; t0 < T_STEPS; t0 += tb) {
        int tcur = T_STEPS - t0 < tb ? T_STEPS - t0 : tb;
        int nrows = tcur * NODE_NUM;
        int gr0 = t0 * NODE_NUM;
        int grLim = gr0 + nrows;
        zero_dup_kernel   <<<nrows / 4, 256, 0, stream>>>(table, idxp, gr0, t0);
        scatter_dup_kernel<<<nrows, E, 0, stream>>>(table, x, idxp, gr0, t0);
        mlp_kernel<<<(nrows + ROWS - 1) / ROWS, 256, 0, stream>>>(
            table, x, bx, idxp, lnd_s, lnd_b, b1d, b2d,
            lnu_s, lnu_b, b1u, b2u, out, gr0, t0, grLim);
    }
}

// Round 2
// 281.689 us; speedup vs baseline: 1.0711x; 1.0402x over previous
//
#include <hip/hip_runtime.h>
#include <math.h>

// Problem constants (from setup_inputs):
#define T_STEPS   4
#define NODE_NUM  10000
#define NUM_NODES 50000
#define E         256     // embedding dim
#define TWO_E     512
#define CC        128     // C
#define TWO_C     256
#define ROWS      32      // rows per block in the MLP kernel

typedef short bf16x8 __attribute__((ext_vector_type(8)));   // 8 bf16 = 4 VGPRs
typedef float f32x4  __attribute__((ext_vector_type(4)));   // MFMA accumulator
typedef unsigned short u16x4 __attribute__((ext_vector_type(4)));

#define MFMA16(a, b, c) __builtin_amdgcn_mfma_f32_16x16x32_bf16((a), (b), (c), 0, 0, 0)

// bf16 weights, transposed [N][K], module-scope device global.
// layout (elements): w1t @0 (512x256), w2t @131072 (128x512),
//                    w1ut @196608 (256x128), w2ut @229376 (256x256)
static __device__ unsigned short g_wt[294912];
// per-(t, idx) occurrence count: rows with cnt==1 (~82%) skip the table
// entirely (identity scatter); only cnt>1 rows pay zero+atomicAdd.
static __device__ int g_cnt[T_STEPS * NUM_NODES];
// compacted list of duplicate rows (per time-slab region starting at gr0)
static __device__ int g_dup[T_STEPS * NODE_NUM];
static __device__ int g_ndup[T_STEPS];

__device__ __forceinline__ float geluf(float v) {
    return 0.5f * v * (1.0f + erff(v * 0.70710678118654752440f));
}

// fp32 -> bf16 round-to-nearest-even (finite inputs only)
__device__ __forceinline__ unsigned short f2bf(float f) {
    unsigned int u = __builtin_bit_cast(unsigned int, f);
    u += 0x7fffu + ((u >> 16) & 1u);
    return (unsigned short)(u >> 16);
}

// ---------------- weight prep: fp32 [K][N] -> bf16 [N][K]; zero g_cnt/g_ndup ----
// grid 784 * 256 = 200704 threads covers all sections.
__global__ void prep_weights(const float* __restrict__ W1d, const float* __restrict__ W2d,
                             const float* __restrict__ W1u, const float* __restrict__ W2u) {
    int i = blockIdx.x * 256 + threadIdx.x;       // 0 .. 200703
    if (i < T_STEPS * NUM_NODES) g_cnt[i] = 0;    // 200000 counts
    if (i < T_STEPS) g_ndup[i] = 0;
    if (i < 131072) {  // w1t: [512][256] <- W1d [256][512]
        int n = i >> 8, k = i & 255;
        g_wt[i] = f2bf(W1d[(size_t)k * TWO_E + n]);
    }
    if (i < 65536) {   // w2t: [128][512] <- W2d [512][128]
        int n = i >> 9, k = i & 511;
        g_wt[131072 + i] = f2bf(W2d[(size_t)k * CC + n]);
    }
    if (i < 32768) {   // w1ut: [256][128] <- W1u [128][256]
        int n = i >> 7, k = i & 127;
        g_wt[196608 + i] = f2bf(W1u[(size_t)k * TWO_C + n]);
    }
    if (i < 65536) {   // w2ut: [256][256] <- W2u [256][256]
        int n = i >> 8, k = i & 255;
        g_wt[229376 + i] = f2bf(W2u[(size_t)k * E + n]);
    }
}

// ---------------- count occurrences of each (t, idx) ----------------
__global__ void count_kernel(const int* __restrict__ indices) {
    int gr = blockIdx.x * 256 + threadIdx.x;
    if (gr < T_STEPS * NODE_NUM) {
        int t = gr / NODE_NUM;
        atomicAdd(&g_cnt[t * NUM_NODES + indices[gr]], 1);
    }
}

// ---------------- compact dup rows into list + zero their table rows ----------------
// One thread per row. Dup-row zeroing is idempotent (all writers store 0).
__global__ void compact_zero_kernel(float* __restrict__ table,
                                    const int* __restrict__ indices,
                                    int gr0, int t0, int grLim, int slab) {
    int gr = gr0 + blockIdx.x * 256 + threadIdx.x;
    if (gr >= grLim) return;
    int t = gr / NODE_NUM;
    int idx = indices[gr];
    if (g_cnt[t * NUM_NODES + idx] < 2) return;
    int pos = atomicAdd(&g_ndup[slab], 1);
    g_dup[gr0 + pos] = gr;
    float4* rp = reinterpret_cast<float4*>(&table[((size_t)(t - t0) * NUM_NODES + idx) * E]);
    float4 z = make_float4(0.f, 0.f, 0.f, 0.f);
    #pragma unroll
    for (int k = 0; k < 64; ++k) rp[k] = z;
}

// ---------------- scatter-add for DUP rows only, from the compacted list ----------------
__global__ void scatter_list_kernel(float* __restrict__ table,
                                    const float* __restrict__ x,
                                    const int* __restrict__ indices,
                                    int gr0, int t0, int slab) {
    int nd = g_ndup[slab];
    for (int e = blockIdx.x; e < nd; e += gridDim.x) {
        int gr = g_dup[gr0 + e];
        int t = gr / NODE_NUM;
        int idx = indices[gr];
        atomicAdd(&table[((size_t)(t - t0) * NUM_NODES + idx) * E + threadIdx.x],
                  x[(size_t)gr * E + threadIdx.x]);
    }
}

// ---------------- fused gather -> LN_d -> MLP_d -> LN_u -> MLP_u ----------------
// 32 rows/block, 256 threads (4 waves). bf16 MFMA 16x16x32, fp32 accumulate.
// LN_d is done in registers (no fp32 staging buffer); all LDS buffers alias one
// 33280-byte region with barrier-enforced liveness:
//   [0,16896)      Xs  bf16 [32][264]   phase-1 out, GEMM1 A-in
//   [0,33280)      H1  bf16 [32][520]   GEMM1 out, GEMM2 A-in   (over Xs)
//   [0,16896)      H2f f32  [32][132]   GEMM2 out, LN_u in      (over H1)
//   [16896,25600)  H2b bf16 [32][136]   LN_u out, GEMM3 A-in    (over dead H1)
//   [0,16896)      G1  bf16 [32][264]   GEMM3 out, GEMM4 A-in   (over dead H2f)
// 33280 B -> 4 blocks/CU; launch_bounds(256,4) keeps VGPR <= 128 to match.
__global__ __launch_bounds__(256, 4)
void mlp_kernel(const float* __restrict__ table,
                const float* __restrict__ x,
                const float* __restrict__ batched_x,
                const int* __restrict__ indices,
                const float* __restrict__ lnd_s, const float* __restrict__ lnd_b,
                const float* __restrict__ b1d, const float* __restrict__ b2d,
                const float* __restrict__ lnu_s, const float* __restrict__ lnu_b,
                const float* __restrict__ b1u, const float* __restrict__ b2u,
                float* __restrict__ out,
                int gr0, int t0, int grLim) {
    __shared__ __align__(16) unsigned char smem[33280];

    unsigned short* Xs  = (unsigned short*)smem;                // [32][264]
    unsigned short* H1  = (unsigned short*)smem;                // [32][520]
    float*          H2f = (float*)smem;                         // [32][132]
    unsigned short* H2b = (unsigned short*)(smem + 16896);      // [32][136]
    unsigned short* G1  = (unsigned short*)smem;                // [32][264]

    const unsigned short* w1t  = g_wt;
    const unsigned short* w2t  = g_wt + 131072;
    const unsigned short* w1ut = g_wt + 196608;
    const unsigned short* w2ut = g_wt + 229376;

    const int tid = threadIdx.x;
    const int w = tid >> 6, lane = tid & 63;
    const int l16 = lane & 15, quad = lane >> 4;
    const int grb = gr0 + blockIdx.x * ROWS;

    // ---- phase 1: gather + LN_d entirely in registers, write bf16 Xs ----
    {
        const int row = tid >> 3, l8 = tid & 7;
        int gr = grb + row;
        if (gr >= grLim) gr = grLim - 1;      // clamped dup row; out-store guarded later
        const int t = gr / NODE_NUM;
        const int idx = indices[gr];
        // unique index (~82%): row input is just x[gr]; dup: read the summed table row
        const float* src = (g_cnt[t * NUM_NODES + idx] > 1)
            ? (table + ((size_t)(t - t0) * NUM_NODES + idx) * E)
            : (x + (size_t)gr * E);
        const float* bxp = batched_x + (size_t)idx * E;
        float v[32];
        float s = 0.f, sq = 0.f;
        #pragma unroll
        for (int k = 0; k < 8; ++k) {
            const int c = k * 32 + l8 * 4;
            float4 a = *reinterpret_cast<const float4*>(src + c);
            float4 b = *reinterpret_cast<const float4*>(bxp + c);
            float4 u;
            u.x = a.x + b.x; u.y = a.y + b.y; u.z = a.z + b.z; u.w = a.w + b.w;
            v[k*4+0] = u.x; v[k*4+1] = u.y; v[k*4+2] = u.z; v[k*4+3] = u.w;
            s  += u.x + u.y + u.z + u.w;
            sq += u.x*u.x + u.y*u.y + u.z*u.z + u.w*u.w;
        }
        s  += __shfl_xor(s, 1);  s  += __shfl_xor(s, 2);  s  += __shfl_xor(s, 4);
        sq += __shfl_xor(sq, 1); sq += __shfl_xor(sq, 2); sq += __shfl_xor(sq, 4);
        const float mu = s * (1.0f / E);
        const float rs = rsqrtf(sq * (1.0f / E) - mu * mu + 1e-5f);
        #pragma unroll
        for (int k = 0; k < 8; ++k) {
            const int c = k * 32 + l8 * 4;
            float4 sc = *reinterpret_cast<const float4*>(lnd_s + c);
            float4 bi = *reinterpret_cast<const float4*>(lnd_b + c);
            u16x4 o;
            o.x = f2bf((v[k*4+0] - mu) * rs * sc.x + bi.x);
            o.y = f2bf((v[k*4+1] - mu) * rs * sc.y + bi.y);
            o.z = f2bf((v[k*4+2] - mu) * rs * sc.z + bi.z);
            o.w = f2bf((v[k*4+3] - mu) * rs * sc.w + bi.w);
            *reinterpret_cast<u16x4*>(&Xs[row * 264 + c]) = o;
        }
    }
    __syncthreads();   // A: Xs ready

    // ---- GEMM1: H1[32][512] = gelu(Xs @ W1d + b1d), K=256 ----
    {
        bf16x8 af[2][8];
        #pragma unroll
        for (int mt = 0; mt < 2; ++mt) {
            const unsigned short* base = Xs + (l16 + 16 * mt) * 264 + quad * 8;
            #pragma unroll
            for (int ks = 0; ks < 8; ++ks)
                af[mt][ks] = *reinterpret_cast<const bf16x8*>(base + ks * 32);
        }
        __syncthreads();   // B: Xs reads done; H1 may overwrite it
        #pragma unroll
        for (int nt_ = 0; nt_ < 8; ++nt_) {
            int n = (w * 8 + nt_) * 16 + l16;
            const unsigned short* bp = w1t + (size_t)n * 256 + quad * 8;
            f32x4 a0 = {0.f, 0.f, 0.f, 0.f}, a1 = {0.f, 0.f, 0.f, 0.f};
            #pragma unroll
            for (int ks = 0; ks < 8; ++ks) {
                bf16x8 b = *reinterpret_cast<const bf16x8*>(bp + ks * 32);
                a0 = MFMA16(af[0][ks], b, a0);
                a1 = MFMA16(af[1][ks], b, a1);
            }
            float bias = b1d[n];
            #pragma unroll
            for (int reg = 0; reg < 4; ++reg) {
                int r = quad * 4 + reg;
                H1[r * 520 + n]        = f2bf(geluf(a0[reg] + bias));
                H1[(r + 16) * 520 + n] = f2bf(geluf(a1[reg] + bias));
            }
        }
    }
    __syncthreads();   // C: H1 ready

    // ---- GEMM2: H2f[32][128] = H1 @ W2d + b2d (fp32 out), K=512 ----
    {
        f32x4 acc2[2][2];
        #pragma unroll
        for (int i = 0; i < 2; ++i)
            #pragma unroll
            for (int j = 0; j < 2; ++j) acc2[i][j] = (f32x4){0.f, 0.f, 0.f, 0.f};
        bf16x8 af2[2][8];
        // kh = 0
        #pragma unroll
        for (int mt = 0; mt < 2; ++mt) {
            const unsigned short* base = H1 + (l16 + 16 * mt) * 520 + quad * 8;
            #pragma unroll
            for (int ks = 0; ks < 8; ++ks)
                af2[mt][ks] = *reinterpret_cast<const bf16x8*>(base + ks * 32);
        }
        #pragma unroll
        for (int nt2 = 0; nt2 < 2; ++nt2) {
            int n = (w * 2 + nt2) * 16 + l16;
            const unsigned short* bp = w2t + (size_t)n * 512 + quad * 8;
            #pragma unroll
            for (int ks = 0; ks < 8; ++ks) {
                bf16x8 b = *reinterpret_cast<const bf16x8*>(bp + ks * 32);
                acc2[nt2][0] = MFMA16(af2[0][ks], b, acc2[nt2][0]);
                acc2[nt2][1] = MFMA16(af2[1][ks], b, acc2[nt2][1]);
            }
        }
        // kh = 1
        #pragma unroll
        for (int mt = 0; mt < 2; ++mt) {
            const unsigned short* base = H1 + (l16 + 16 * mt) * 520 + 256 + quad * 8;
            #pragma unroll
            for (int ks = 0; ks < 8; ++ks)
                af2[mt][ks] = *reinterpret_cast<const bf16x8*>(base + ks * 32);
        }
        __syncthreads();   // D: all H1 reads done; H2f may overwrite it
        #pragma unroll
        for (int nt2 = 0; nt2 < 2; ++nt2) {
            int n = (w * 2 + nt2) * 16 + l16;
            const unsigned short* bp = w2t + (size_t)n * 512 + 256 + quad * 8;
            #pragma unroll
            for (int ks = 0; ks < 8; ++ks) {
                bf16x8 b = *reinterpret_cast<const bf16x8*>(bp + ks * 32);
                acc2[nt2][0] = MFMA16(af2[0][ks], b, acc2[nt2][0]);
                acc2[nt2][1] = MFMA16(af2[1][ks], b, acc2[nt2][1]);
            }
        }
        #pragma unroll
        for (int nt2 = 0; nt2 < 2; ++nt2) {
            int n = (w * 2 + nt2) * 16 + l16;
            float bias = b2d[n];
            #pragma unroll
            for (int mt = 0; mt < 2; ++mt)
                #pragma unroll
                for (int reg = 0; reg < 4; ++reg) {
                    int r = mt * 16 + quad * 4 + reg;
                    H2f[r * 132 + n] = acc2[nt2][mt][reg] + bias;
                }
        }
    }
    __syncthreads();   // E: H2f ready

    // ---- LN_u (C=128): 8 lanes/row, cvt bf16 -> H2b (disjoint region) ----
    {
        int row = tid >> 3, l8 = tid & 7;
        float s = 0.f, sq = 0.f;
        #pragma unroll
        for (int k = 0; k < 16; ++k) {
            float v = H2f[row * 132 + k * 8 + l8];
            s += v; sq += v * v;
        }
        s  += __shfl_xor(s, 1);  s  += __shfl_xor(s, 2);  s  += __shfl_xor(s, 4);
        sq += __shfl_xor(sq, 1); sq += __shfl_xor(sq, 2); sq += __shfl_xor(sq, 4);
        float mu = s * (1.0f / CC);
        float var = sq * (1.0f / CC) - mu * mu;
        float rs = rsqrtf(var + 1e-5f);
        #pragma unroll
        for (int k = 0; k < 16; ++k) {
            int c = k * 8 + l8;
            float v = (H2f[row * 132 + c] - mu) * rs * lnu_s[c] + lnu_b[c];
            H2b[row * 136 + c] = f2bf(v);
        }
    }
    __syncthreads();   // F: H2b ready; H2f dead

    // ---- GEMM3: G1[32][256] = gelu(H2b @ W1u + b1u), K=128 ----
    {
        bf16x8 af3[2][4];
        #pragma unroll
        for (int mt = 0; mt < 2; ++mt) {
            const unsigned short* base = H2b + (l16 + 16 * mt) * 136 + quad * 8;
            #pragma unroll
            for (int ks = 0; ks < 4; ++ks)
                af3[mt][ks] = *reinterpret_cast<const bf16x8*>(base + ks * 32);
        }
        #pragma unroll
        for (int nt_ = 0; nt_ < 4; ++nt_) {
            int n = (w * 4 + nt_) * 16 + l16;
            const unsigned short* bp = w1ut + (size_t)n * 128 + quad * 8;
            f32x4 a0 = {0.f, 0.f, 0.f, 0.f}, a1 = {0.f, 0.f, 0.f, 0.f};
            #pragma unroll
            for (int ks = 0; ks < 4; ++ks) {
                bf16x8 b = *reinterpret_cast<const bf16x8*>(bp + ks * 32);
                a0 = MFMA16(af3[0][ks], b, a0);
                a1 = MFMA16(af3[1][ks], b, a1);
            }
            float bias = b1u[n];
            #pragma unroll
            for (int reg = 0; reg < 4; ++reg) {
                int r = quad * 4 + reg;
                G1[r * 264 + n]        = f2bf(geluf(a0[reg] + bias));   // G1 over dead H2f
                G1[(r + 16) * 264 + n] = f2bf(geluf(a1[reg] + bias));
            }
        }
    }
    __syncthreads();   // G: G1 ready

    // ---- GEMM4: out[32][256] = G1 @ W2u + b2u (fp32 global), K=256 ----
    {
        bf16x8 af4[2][8];
        #pragma unroll
        for (int mt = 0; mt < 2; ++mt) {
            const unsigned short* base = G1 + (l16 + 16 * mt) * 264 + quad * 8;
            #pragma unroll
            for (int ks = 0; ks < 8; ++ks)
                af4[mt][ks] = *reinterpret_cast<const bf16x8*>(base + ks * 32);
        }
        #pragma unroll
        for (int nt_ = 0; nt_ < 4; ++nt_) {
            int n = (w * 4 + nt_) * 16 + l16;
            const unsigned short* bp = w2ut + (size_t)n * 256 + quad * 8;
            f32x4 a0 = {0.f, 0.f, 0.f, 0.f}, a1 = {0.f, 0.f, 0.f, 0.f};
            #pragma unroll
            for (int ks = 0; ks < 8; ++ks) {
                bf16x8 b = *reinterpret_cast<const bf16x8*>(bp + ks * 32);
                a0 = MFMA16(af4[0][ks], b, a0);
                a1 = MFMA16(af4[1][ks], b, a1);
            }
            float bias = b2u[n];
            #pragma unroll
            for (int reg = 0; reg < 4; ++reg) {
                int r = quad * 4 + reg;
                int g0 = grb + r, g1 = grb + r + 16;
                if (g0 < grLim) out[(size_t)g0 * E + n] = a0[reg] + bias;
                if (g1 < grLim) out[(size_t)g1 * E + n] = a1[reg] + bias;
            }
        }
    }
}

extern "C" void kernel_launch(void* const* d_in, const int* in_sizes, int n_in,
                              void* d_out, int out_size, void* d_ws, size_t ws_size,
                              hipStream_t stream) {
    const float* x     = (const float*)d_in[0];
    const float* bx    = (const float*)d_in[1];
    const int*   idxp  = (const int*)  d_in[2];
    const float* lnd_s = (const float*)d_in[3];
    const float* lnd_b = (const float*)d_in[4];
    const float* W1d   = (const float*)d_in[5];
    const float* b1d   = (const float*)d_in[6];
    const float* W2d   = (const float*)d_in[7];
    const float* b2d   = (const float*)d_in[8];
    const float* lnu_s = (const float*)d_in[9];
    const float* lnu_b = (const float*)d_in[10];
    const float* W1u   = (const float*)d_in[11];
    const float* b1u   = (const float*)d_in[12];
    const float* W2u   = (const float*)d_in[13];
    const float* b2u   = (const float*)d_in[14];
    float* out = (float*)d_out;
    float* table = (float*)d_ws;     // full ws for table slices (weights in g_wt)

    const size_t slice_bytes = (size_t)NUM_NODES * E * sizeof(float);
    int tb = (int)(ws_size / slice_bytes);
    if (tb < 1) tb = 1;              // prior rounds passed with this assumption
    if (tb > T_STEPS) tb = T_STEPS;

    // weight transpose/cvt + g_cnt/g_ndup zeroing (fused), then occurrence count
    prep_weights<<<784, 256, 0, stream>>>(W1d, W2d, W1u, W2u);
    count_kernel<<<(T_STEPS * NODE_NUM + 255) / 256, 256, 0, stream>>>(idxp);

    for (int t0 = 0; t0 < T_STEPS; t0 += tb) {
        int tcur = T_STEPS - t0 < tb ? T_STEPS - t0 : tb;
        int nrows = tcur * NODE_NUM;
        int gr0 = t0 * NODE_NUM;
        int grLim = gr0 + nrows;
        int slab = t0 / tb;
        compact_zero_kernel<<<(nrows + 255) / 256, 256, 0, stream>>>(
            table, idxp, gr0, t0, grLim, slab);
        scatter_list_kernel<<<1024, E, 0, stream>>>(table, x, idxp, gr0, t0, slab);
        mlp_kernel<<<(nrows + ROWS - 1) / ROWS, 256, 0, stream>>>(
            table, x, bx, idxp, lnd_s, lnd_b, b1d, b2d,
            lnu_s, lnu_b, b1u, b2u, out, gr0, t0, grLim);
    }
}